// Round 3
// baseline (763.518 us; speedup 1.0000x reference)
//
#include <hip/hip_runtime.h>
#include <math.h>

#define T_TOK 8192
#define DM 1024
#define DF 2048
#define NE 16
#define TK 2
#define CAP 1280

typedef __bf16 bf16x8 __attribute__((ext_vector_type(8)));
typedef float f32x4 __attribute__((ext_vector_type(4)));

__device__ __forceinline__ unsigned short f2bf(float f) {
  unsigned int u = __float_as_uint(f);
  unsigned int r = (u + 0x7fffu + ((u >> 16) & 1u)) >> 16;
  return (unsigned short)r;
}

__device__ __forceinline__ float bf2f(unsigned short u) {
  return __uint_as_float((unsigned int)u << 16);
}

__device__ __forceinline__ void async_copy16(const void* g, void* l) {
  __builtin_amdgcn_global_load_lds(
      (const __attribute__((address_space(1))) void*)g,
      (__attribute__((address_space(3))) void*)l, 16, 0, 0);
}

// ---------------- transpose + fp32->bf16 convert: in (R x Cc) fp32 -> out (Cc x R) bf16
__global__ __launch_bounds__(256) void transpose_conv_kernel(
    const float* __restrict__ in, unsigned short* __restrict__ out, int R, int Cc) {
  __shared__ unsigned short tl[64][72];
  size_t eoff = (size_t)blockIdx.z * R * Cc;
  in += eoff; out += eoff;
  int c0 = blockIdx.x * 64, r0 = blockIdx.y * 64;
  int t = threadIdx.x;
#pragma unroll
  for (int i = 0; i < 4; i++) {
    int r = (t >> 4) + i * 16;
    int c = (t & 15) * 4;
    float4 v = *(const float4*)(in + (size_t)(r0 + r) * Cc + c0 + c);
    tl[c + 0][r] = f2bf(v.x);
    tl[c + 1][r] = f2bf(v.y);
    tl[c + 2][r] = f2bf(v.z);
    tl[c + 3][r] = f2bf(v.w);
  }
  __syncthreads();
#pragma unroll
  for (int i = 0; i < 2; i++) {
    int c = (t >> 3) + i * 32;
    int r = (t & 7) * 8;
    *(int4*)(out + (size_t)(c0 + c) * R + r0 + r) = *(const int4*)&tl[c][r];
  }
}

// ---------------- gating: 128 blocks, 64 tokens/block (16 per wave); gw staged in LDS once
__global__ __launch_bounds__(256) void gate_kernel(
    const float* __restrict__ x, const float* __restrict__ gw,
    int* __restrict__ sel, float* __restrict__ wts) {
  __shared__ float sgw[NE * DM];
  int tid = threadIdx.x, lane = tid & 63, wv = tid >> 6;
  for (int i = tid; i < NE * DM / 4; i += 256)
    ((float4*)sgw)[i] = ((const float4*)gw)[i];
  __syncthreads();
  const float4* g4 = (const float4*)sgw;
  for (int it = 0; it < 16; it++) {
    int t = blockIdx.x * 64 + wv * 16 + it;
    const float4* xr = (const float4*)(x + (size_t)t * DM);
    float4 xv[4];
#pragma unroll
    for (int j = 0; j < 4; j++) xv[j] = xr[j * 64 + lane];
    float acc[NE];
#pragma unroll
    for (int e = 0; e < NE; e++) {
      float s = 0.f;
#pragma unroll
      for (int j = 0; j < 4; j++) {
        float4 g = g4[e * 256 + j * 64 + lane];
        s += xv[j].x * g.x + xv[j].y * g.y + xv[j].z * g.z + xv[j].w * g.w;
      }
      acc[e] = s;
    }
#pragma unroll
    for (int e = 0; e < NE; e++) {
      float v = acc[e];
#pragma unroll
      for (int off = 32; off > 0; off >>= 1) v += __shfl_xor(v, off);
      acc[e] = v;
    }
    if (lane == 0) {
      float p[NE];
#pragma unroll
      for (int e = 0; e < NE; e++) p[e] = 1.f / (1.f + expf(-acc[e]));
      int i0 = 0;
#pragma unroll
      for (int e = 1; e < NE; e++) if (p[e] > p[i0]) i0 = e;
      int i1 = (i0 == 0) ? 1 : 0;
#pragma unroll
      for (int e = 0; e < NE; e++) if (e != i0 && p[e] > p[i1]) i1 = e;
      float v0 = p[i0], v1 = p[i1], s = v0 + v1 + 1e-6f;
      sel[2 * t] = i0; sel[2 * t + 1] = i1;
      wts[2 * t] = v0 / s; wts[2 * t + 1] = v1 / s;
    }
  }
}

// ---------------- single-barrier rank/capacity scan: one block (1024 thr) per expert
__global__ __launch_bounds__(1024) void scan_kernel(
    const int* __restrict__ sel, int* __restrict__ pos_slot,
    int* __restrict__ exp_tok, int* __restrict__ counts) {
  int e = blockIdx.x;
  int tid = threadIdx.x, lane = tid & 63, wv = tid >> 6;
  __shared__ int wtot[16];
  int local[16];
  unsigned int flags = 0;
  int run = 0;
#pragma unroll
  for (int it = 0; it < 16; it++) {
    int p = wv * 1024 + it * 64 + lane;
    int f = (sel[p] == e) ? 1 : 0;
    unsigned long long b = __ballot(f);
    if (f) { flags |= 1u << it; local[it] = run + __popcll(b & ((1ull << lane) - 1ull)); }
    run += __popcll(b);
  }
  if (lane == 0) wtot[wv] = run;
  __syncthreads();
  int base = 0, total = 0;
#pragma unroll
  for (int i = 0; i < 16; i++) {
    int v = wtot[i];
    if (i < wv) base += v;
    total += v;
  }
#pragma unroll
  for (int it = 0; it < 16; it++) {
    if (flags & (1u << it)) {
      int p = wv * 1024 + it * 64 + lane;
      int rank = base + local[it];
      if (rank < CAP) {
        pos_slot[p] = e * CAP + rank;
        exp_tok[e * CAP + rank] = p;
      } else {
        pos_slot[p] = -1;
      }
    }
  }
  if (tid == 0) counts[e] = total < CAP ? total : CAP;
}

// ---------------- gather tokens into padded [E,CAP,DM] bf16 (zero-fill past count)
__global__ __launch_bounds__(128) void gather_kernel(
    const float* __restrict__ x, const int* __restrict__ exp_tok,
    const int* __restrict__ counts, unsigned short* __restrict__ Xp) {
  int i = blockIdx.x, e = blockIdx.y;
  int tid = threadIdx.x;
  unsigned short* dst = Xp + ((size_t)e * CAP + i) * DM;
  int4 pk = make_int4(0, 0, 0, 0);
  if (i < counts[e]) {
    int p = exp_tok[e * CAP + i];
    int t = p >> 1;
    const float4* src = (const float4*)(x + (size_t)t * DM);
    float4 v0 = src[tid * 2];
    float4 v1 = src[tid * 2 + 1];
    union { unsigned short u[8]; int4 v; } q;
    q.u[0] = f2bf(v0.x); q.u[1] = f2bf(v0.y); q.u[2] = f2bf(v0.z); q.u[3] = f2bf(v0.w);
    q.u[4] = f2bf(v1.x); q.u[5] = f2bf(v1.y); q.u[6] = f2bf(v1.z); q.u[7] = f2bf(v1.w);
    pk = q.v;
  }
  ((int4*)dst)[tid] = pk;
}

// ---------------- bf16 MFMA GEMM (m97 structure + XOR swizzle + count-aware block skip)
template <bool GELU>
__global__ __launch_bounds__(256) void gemm_kernel(
    const unsigned short* __restrict__ A, const unsigned short* __restrict__ Bt,
    unsigned short* __restrict__ C, const int* __restrict__ counts,
    int N, int K, size_t sA, size_t sB, size_t sC) {
  int e = blockIdx.z;
  int m0 = blockIdx.y * 128;
  int cnt = counts[e];
  if (m0 >= cnt) return;  // rows are zero / never consumed downstream
  __shared__ unsigned short As[128 * 32];
  __shared__ unsigned short Bs[128 * 32];
  A += (size_t)e * sA;
  Bt += (size_t)e * sB;
  C += (size_t)e * sC;
  int n0 = blockIdx.x * 128;
  int tid = threadIdx.x;
  int lane = tid & 63;
  int wv = tid >> 6;
  int wm = (wv >> 1) * 64, wn = (wv & 1) * 64;
  int qd = lane >> 4, lm = lane & 15;
  int sa = (lm >> 1) & 3;
  int chunk = (tid & 3) ^ ((tid >> 3) & 3);

  const unsigned short* a0 = A + (size_t)(m0 + (tid >> 2)) * K + chunk * 8;
  const unsigned short* a1 = a0 + (size_t)64 * K;
  const unsigned short* b0 = Bt + (size_t)(n0 + (tid >> 2)) * K + chunk * 8;
  const unsigned short* b1 = b0 + (size_t)64 * K;
  char* lAs = (char*)As;
  char* lBs = (char*)Bs;

  f32x4 acc[4][4] = {};
  for (int k0 = 0; k0 < K; k0 += 32) {
    __syncthreads();
    async_copy16(a0 + k0, lAs + tid * 16);
    async_copy16(a1 + k0, lAs + (tid + 256) * 16);
    async_copy16(b0 + k0, lBs + tid * 16);
    async_copy16(b1 + k0, lBs + (tid + 256) * 16);
    __syncthreads();
    bf16x8 af[4], bfr[4];
#pragma unroll
    for (int i = 0; i < 4; i++)
      af[i] = *(const bf16x8*)(lAs + (wm + i * 16 + lm) * 64 + (qd ^ sa) * 16);
#pragma unroll
    for (int j = 0; j < 4; j++)
      bfr[j] = *(const bf16x8*)(lBs + (wn + j * 16 + lm) * 64 + (qd ^ sa) * 16);
#pragma unroll
    for (int i = 0; i < 4; i++)
#pragma unroll
      for (int j = 0; j < 4; j++)
        acc[i][j] = __builtin_amdgcn_mfma_f32_16x16x32_bf16(af[i], bfr[j], acc[i][j], 0, 0, 0);
  }
#pragma unroll
  for (int i = 0; i < 4; i++) {
    int row = m0 + wm + i * 16 + qd * 4;
#pragma unroll
    for (int j = 0; j < 4; j++) {
      int col = n0 + wn + j * 16 + lm;
#pragma unroll
      for (int r = 0; r < 4; r++) {
        float v = acc[i][j][r];
        if (GELU) v = 0.5f * v * (1.f + erff(v * 0.70710678118f));
        C[(size_t)(row + r) * N + col] = f2bf(v);
      }
    }
  }
}

// ---------------- weighted combine back to token order (bf16 outp -> fp32 out)
__global__ __launch_bounds__(128) void combine_kernel(
    const unsigned short* __restrict__ outp, const int* __restrict__ pos_slot,
    const float* __restrict__ wts, float* __restrict__ out) {
  int t = blockIdx.x, tid = threadIdx.x;
  float acc[8] = {0.f, 0.f, 0.f, 0.f, 0.f, 0.f, 0.f, 0.f};
#pragma unroll
  for (int k = 0; k < 2; k++) {
    int p = 2 * t + k;
    int s = pos_slot[p];
    if (s >= 0) {
      float w = wts[p];
      union { int4 v; unsigned short u[8]; } q;
      q.v = *(const int4*)(outp + (size_t)s * DM + tid * 8);
#pragma unroll
      for (int i = 0; i < 8; i++) acc[i] += w * bf2f(q.u[i]);
    }
  }
  float4* dst = (float4*)(out + (size_t)t * DM + tid * 8);
  dst[0] = make_float4(acc[0], acc[1], acc[2], acc[3]);
  dst[1] = make_float4(acc[4], acc[5], acc[6], acc[7]);
}

extern "C" void kernel_launch(void* const* d_in, const int* in_sizes, int n_in,
                              void* d_out, int out_size, void* d_ws, size_t ws_size,
                              hipStream_t stream) {
  (void)in_sizes; (void)n_in; (void)out_size; (void)ws_size;
  const float* x  = (const float*)d_in[0];
  const float* gw = (const float*)d_in[1];
  const float* w1 = (const float*)d_in[2];
  const float* w2 = (const float*)d_in[3];
  float* out = (float*)d_out;

  char* ws = (char*)d_ws;
  unsigned short* w1t = (unsigned short*)ws; ws += (size_t)NE * DM * DF * 2;
  unsigned short* w2t = (unsigned short*)ws; ws += (size_t)NE * DF * DM * 2;
  unsigned short* Xp  = (unsigned short*)ws; ws += (size_t)NE * CAP * DM * 2;
  unsigned short* H   = (unsigned short*)ws; ws += (size_t)NE * CAP * DF * 2;
  unsigned short* outp = (unsigned short*)ws; ws += (size_t)NE * CAP * DM * 2;
  int* sel = (int*)ws;       ws += (size_t)T_TOK * TK * 4;
  float* wts = (float*)ws;   ws += (size_t)T_TOK * TK * 4;
  int* pos_slot = (int*)ws;  ws += (size_t)T_TOK * TK * 4;
  int* exp_tok = (int*)ws;   ws += (size_t)NE * CAP * 4;
  int* counts = (int*)ws;    ws += (size_t)NE * 4;

  // weights: fp32 -> bf16, transposed to [N,K] per expert
  transpose_conv_kernel<<<dim3(DF / 64, DM / 64, NE), 256, 0, stream>>>(w1, w1t, DM, DF);
  transpose_conv_kernel<<<dim3(DM / 64, DF / 64, NE), 256, 0, stream>>>(w2, w2t, DF, DM);
  // routing
  gate_kernel<<<T_TOK / 64, 256, 0, stream>>>(x, gw, sel, wts);
  scan_kernel<<<NE, 1024, 0, stream>>>(sel, pos_slot, exp_tok, counts);
  gather_kernel<<<dim3(CAP, NE), 128, 0, stream>>>(x, exp_tok, counts, Xp);
  // expert FFN
  gemm_kernel<true><<<dim3(DF / 128, CAP / 128, NE), 256, 0, stream>>>(
      Xp, w1t, H, counts, DF, DM, (size_t)CAP * DM, (size_t)DM * DF, (size_t)CAP * DF);
  gemm_kernel<false><<<dim3(DM / 128, CAP / 128, NE), 256, 0, stream>>>(
      H, w2t, outp, counts, DM, DF, (size_t)CAP * DF, (size_t)DF * DM, (size_t)CAP * DM);
  // un-permute + weighted sum
  combine_kernel<<<T_TOK, 128, 0, stream>>>(outp, pos_slot, wts, out);
}

// Round 4
// 660.630 us; speedup vs baseline: 1.1557x; 1.1557x over previous
//
#include <hip/hip_runtime.h>
#include <math.h>

#define T_TOK 8192
#define DM 1024
#define DF 2048
#define NE 16
#define TK 2
#define CAP 1280

typedef __bf16 bf16x8 __attribute__((ext_vector_type(8)));
typedef float f32x4 __attribute__((ext_vector_type(4)));
typedef unsigned short us4 __attribute__((ext_vector_type(4)));

__device__ __forceinline__ unsigned short f2bf(float f) {
  unsigned int u = __float_as_uint(f);
  unsigned int r = (u + 0x7fffu + ((u >> 16) & 1u)) >> 16;
  return (unsigned short)r;
}

__device__ __forceinline__ float bf2f(unsigned short u) {
  return __uint_as_float((unsigned int)u << 16);
}

__device__ __forceinline__ void async_copy16(const void* g, void* l) {
  __builtin_amdgcn_global_load_lds(
      (const __attribute__((address_space(1))) void*)g,
      (__attribute__((address_space(3))) void*)l, 16, 0, 0);
}

// ---------------- fused prep: gate (blocks 0..2047) + w1/w2 transpose+convert
#define GATE_BLKS (T_TOK / 4)
__global__ __launch_bounds__(256) void prep_kernel(
    const float* __restrict__ x, const float* __restrict__ gw,
    const float* __restrict__ w1, const float* __restrict__ w2,
    unsigned short* __restrict__ w1t, unsigned short* __restrict__ w2t,
    int* __restrict__ sel, float* __restrict__ wts) {
  __shared__ unsigned short tl[64][72];
  int b = blockIdx.x;
  int tid = threadIdx.x;
  if (b < GATE_BLKS) {
    // ---- gate: one token per wave, gw read via L1/L2
    int lane = tid & 63, wv = tid >> 6;
    int t = b * 4 + wv;
    const float4* xr = (const float4*)(x + (size_t)t * DM);
    float4 xv[4];
#pragma unroll
    for (int j = 0; j < 4; j++) xv[j] = xr[j * 64 + lane];
    const float4* g4 = (const float4*)gw;
    float acc[NE];
#pragma unroll
    for (int e = 0; e < NE; e++) {
      float s = 0.f;
#pragma unroll
      for (int j = 0; j < 4; j++) {
        float4 g = g4[e * 256 + j * 64 + lane];
        s += xv[j].x * g.x + xv[j].y * g.y + xv[j].z * g.z + xv[j].w * g.w;
      }
      acc[e] = s;
    }
#pragma unroll
    for (int e = 0; e < NE; e++) {
      float v = acc[e];
#pragma unroll
      for (int off = 32; off > 0; off >>= 1) v += __shfl_xor(v, off);
      acc[e] = v;
    }
    if (lane == 0) {
      float p[NE];
#pragma unroll
      for (int e = 0; e < NE; e++) p[e] = 1.f / (1.f + expf(-acc[e]));
      int i0 = 0;
#pragma unroll
      for (int e = 1; e < NE; e++) if (p[e] > p[i0]) i0 = e;
      int i1 = (i0 == 0) ? 1 : 0;
#pragma unroll
      for (int e = 0; e < NE; e++) if (e != i0 && p[e] > p[i1]) i1 = e;
      float v0 = p[i0], v1 = p[i1], s = v0 + v1 + 1e-6f;
      sel[2 * t] = i0; sel[2 * t + 1] = i1;
      wts[2 * t] = v0 / s; wts[2 * t + 1] = v1 / s;
    }
  } else {
    // ---- transpose+convert 64x64 tile
    int bb = b - GATE_BLKS;
    const float* in; unsigned short* out; int R, Cc, rt, ct, e;
    if (bb < 8192) {  // w1: [DM x DF] per expert -> w1t [DF x DM]
      in = w1; out = w1t; R = DM; Cc = DF;
      e = bb >> 9; int r = bb & 511; rt = r >> 5; ct = r & 31;
    } else {          // w2: [DF x DM] per expert -> w2t [DM x DF]
      bb -= 8192;
      in = w2; out = w2t; R = DF; Cc = DM;
      e = bb >> 9; int r = bb & 511; rt = r >> 4; ct = r & 15;
    }
    size_t eoff = (size_t)e * R * Cc;
    in += eoff; out += eoff;
    int c0 = ct * 64, r0 = rt * 64;
#pragma unroll
    for (int i = 0; i < 4; i++) {
      int r = (tid >> 4) + i * 16;
      int c = (tid & 15) * 4;
      float4 v = *(const float4*)(in + (size_t)(r0 + r) * Cc + c0 + c);
      tl[c + 0][r] = f2bf(v.x);
      tl[c + 1][r] = f2bf(v.y);
      tl[c + 2][r] = f2bf(v.z);
      tl[c + 3][r] = f2bf(v.w);
    }
    __syncthreads();
#pragma unroll
    for (int i = 0; i < 2; i++) {
      int c = (tid >> 3) + i * 32;
      int r = (tid & 7) * 8;
      *(int4*)(out + (size_t)(c0 + c) * R + r0 + r) = *(const int4*)&tl[c][r];
    }
  }
}

// ---------------- single-barrier rank/capacity scan: one block (1024 thr) per expert
__global__ __launch_bounds__(1024) void scan_kernel(
    const int* __restrict__ sel, int* __restrict__ pos_slot,
    int* __restrict__ exp_tok, int* __restrict__ counts) {
  int e = blockIdx.x;
  int tid = threadIdx.x, lane = tid & 63, wv = tid >> 6;
  __shared__ int wtot[16];
  int local[16];
  unsigned int flags = 0;
  int run = 0;
#pragma unroll
  for (int it = 0; it < 16; it++) {
    int p = wv * 1024 + it * 64 + lane;
    int f = (sel[p] == e) ? 1 : 0;
    unsigned long long b = __ballot(f);
    if (f) { flags |= 1u << it; local[it] = run + __popcll(b & ((1ull << lane) - 1ull)); }
    run += __popcll(b);
  }
  if (lane == 0) wtot[wv] = run;
  __syncthreads();
  int base = 0, total = 0;
#pragma unroll
  for (int i = 0; i < 16; i++) {
    int v = wtot[i];
    if (i < wv) base += v;
    total += v;
  }
#pragma unroll
  for (int it = 0; it < 16; it++) {
    if (flags & (1u << it)) {
      int p = wv * 1024 + it * 64 + lane;
      int rank = base + local[it];
      if (rank < CAP) {
        pos_slot[p] = e * CAP + rank;
        exp_tok[e * CAP + rank] = p;
      } else {
        pos_slot[p] = -1;
      }
    }
  }
  if (tid == 0) counts[e] = total < CAP ? total : CAP;
}

// ---------------- gather tokens into padded [E,CAP,DM] bf16 (zero-fill past count)
__global__ __launch_bounds__(128) void gather_kernel(
    const float* __restrict__ x, const int* __restrict__ exp_tok,
    const int* __restrict__ counts, unsigned short* __restrict__ Xp) {
  int i = blockIdx.x, e = blockIdx.y;
  int tid = threadIdx.x;
  unsigned short* dst = Xp + ((size_t)e * CAP + i) * DM;
  int4 pk = make_int4(0, 0, 0, 0);
  if (i < counts[e]) {
    int p = exp_tok[e * CAP + i];
    int t = p >> 1;
    const float4* src = (const float4*)(x + (size_t)t * DM);
    float4 v0 = src[tid * 2];
    float4 v1 = src[tid * 2 + 1];
    union { unsigned short u[8]; int4 v; } q;
    q.u[0] = f2bf(v0.x); q.u[1] = f2bf(v0.y); q.u[2] = f2bf(v0.z); q.u[3] = f2bf(v0.w);
    q.u[4] = f2bf(v1.x); q.u[5] = f2bf(v1.y); q.u[6] = f2bf(v1.z); q.u[7] = f2bf(v1.w);
    pk = q.v;
  }
  ((int4*)dst)[tid] = pk;
}

// ---------------- bf16 MFMA GEMM: A=[M,K] weights^T, Bt=[N=slots,K] acts,
// D[m][n] stored TRANSPOSED to C[n][m] -> per-lane ushort4 packed stores.
template <bool GELU>
__global__ __launch_bounds__(256) void gemm_kernel(
    const unsigned short* __restrict__ A, const unsigned short* __restrict__ Bt,
    unsigned short* __restrict__ C, const int* __restrict__ counts,
    int M, int K, size_t sA, size_t sB, size_t sC) {
  int e = blockIdx.z;
  int n0 = blockIdx.x * 128;  // slot dim
  int cnt = counts[e];
  if (n0 >= cnt) return;  // these slots are zero / never read downstream
  __shared__ unsigned short As[128 * 32];
  __shared__ unsigned short Bs[128 * 32];
  A += (size_t)e * sA;
  Bt += (size_t)e * sB;
  C += (size_t)e * sC;
  int m0 = blockIdx.y * 128;
  int tid = threadIdx.x;
  int lane = tid & 63;
  int wv = tid >> 6;
  int wm = (wv >> 1) * 64, wn = (wv & 1) * 64;
  int qd = lane >> 4, lm = lane & 15;
  int sa = (lm >> 1) & 3;
  int chunk = (tid & 3) ^ ((tid >> 3) & 3);

  const unsigned short* a0 = A + (size_t)(m0 + (tid >> 2)) * K + chunk * 8;
  const unsigned short* a1 = a0 + (size_t)64 * K;
  const unsigned short* b0 = Bt + (size_t)(n0 + (tid >> 2)) * K + chunk * 8;
  const unsigned short* b1 = b0 + (size_t)64 * K;
  char* lAs = (char*)As;
  char* lBs = (char*)Bs;

  f32x4 acc[4][4] = {};
  for (int k0 = 0; k0 < K; k0 += 32) {
    __syncthreads();
    async_copy16(a0 + k0, lAs + tid * 16);
    async_copy16(a1 + k0, lAs + (tid + 256) * 16);
    async_copy16(b0 + k0, lBs + tid * 16);
    async_copy16(b1 + k0, lBs + (tid + 256) * 16);
    __syncthreads();
    bf16x8 af[4], bfr[4];
#pragma unroll
    for (int i = 0; i < 4; i++)
      af[i] = *(const bf16x8*)(lAs + (wm + i * 16 + lm) * 64 + (qd ^ sa) * 16);
#pragma unroll
    for (int j = 0; j < 4; j++)
      bfr[j] = *(const bf16x8*)(lBs + (wn + j * 16 + lm) * 64 + (qd ^ sa) * 16);
#pragma unroll
    for (int i = 0; i < 4; i++)
#pragma unroll
      for (int j = 0; j < 4; j++)
        acc[i][j] = __builtin_amdgcn_mfma_f32_16x16x32_bf16(af[i], bfr[j], acc[i][j], 0, 0, 0);
  }
  // epilogue: D[m=m0+wm+i*16+qd*4+r][n=n0+wn+j*16+lm] -> C[n][m], 8B packed
#pragma unroll
  for (int j = 0; j < 4; j++) {
    int slot = n0 + wn + j * 16 + lm;
    unsigned short* crow = C + (size_t)slot * M;
#pragma unroll
    for (int i = 0; i < 4; i++) {
      int m = m0 + wm + i * 16 + qd * 4;
      us4 pk;
#pragma unroll
      for (int r = 0; r < 4; r++) {
        float v = acc[i][j][r];
        if (GELU) v = 0.5f * v * (1.f + erff(v * 0.70710678118f));
        pk[r] = f2bf(v);
      }
      *(us4*)(crow + m) = pk;
    }
  }
}

// ---------------- weighted combine back to token order (bf16 outp -> fp32 out)
__global__ __launch_bounds__(128) void combine_kernel(
    const unsigned short* __restrict__ outp, const int* __restrict__ pos_slot,
    const float* __restrict__ wts, float* __restrict__ out) {
  int t = blockIdx.x, tid = threadIdx.x;
  float acc[8] = {0.f, 0.f, 0.f, 0.f, 0.f, 0.f, 0.f, 0.f};
#pragma unroll
  for (int k = 0; k < 2; k++) {
    int p = 2 * t + k;
    int s = pos_slot[p];
    if (s >= 0) {
      float w = wts[p];
      union { int4 v; unsigned short u[8]; } q;
      q.v = *(const int4*)(outp + (size_t)s * DM + tid * 8);
#pragma unroll
      for (int i = 0; i < 8; i++) acc[i] += w * bf2f(q.u[i]);
    }
  }
  float4* dst = (float4*)(out + (size_t)t * DM + tid * 8);
  dst[0] = make_float4(acc[0], acc[1], acc[2], acc[3]);
  dst[1] = make_float4(acc[4], acc[5], acc[6], acc[7]);
}

extern "C" void kernel_launch(void* const* d_in, const int* in_sizes, int n_in,
                              void* d_out, int out_size, void* d_ws, size_t ws_size,
                              hipStream_t stream) {
  (void)in_sizes; (void)n_in; (void)out_size; (void)ws_size;
  const float* x  = (const float*)d_in[0];
  const float* gw = (const float*)d_in[1];
  const float* w1 = (const float*)d_in[2];
  const float* w2 = (const float*)d_in[3];
  float* out = (float*)d_out;

  char* ws = (char*)d_ws;
  unsigned short* w1t = (unsigned short*)ws; ws += (size_t)NE * DM * DF * 2;
  unsigned short* w2t = (unsigned short*)ws; ws += (size_t)NE * DF * DM * 2;
  unsigned short* Xp  = (unsigned short*)ws; ws += (size_t)NE * CAP * DM * 2;
  unsigned short* H   = (unsigned short*)ws; ws += (size_t)NE * CAP * DF * 2;
  unsigned short* outp = (unsigned short*)ws; ws += (size_t)NE * CAP * DM * 2;
  int* sel = (int*)ws;       ws += (size_t)T_TOK * TK * 4;
  float* wts = (float*)ws;   ws += (size_t)T_TOK * TK * 4;
  int* pos_slot = (int*)ws;  ws += (size_t)T_TOK * TK * 4;
  int* exp_tok = (int*)ws;   ws += (size_t)NE * CAP * 4;
  int* counts = (int*)ws;    ws += (size_t)NE * 4;

  // fused: gate + both weight transposes (independent work, one launch)
  prep_kernel<<<GATE_BLKS + 16384, 256, 0, stream>>>(x, gw, w1, w2, w1t, w2t, sel, wts);
  scan_kernel<<<NE, 1024, 0, stream>>>(sel, pos_slot, exp_tok, counts);
  gather_kernel<<<dim3(CAP, NE), 128, 0, stream>>>(x, exp_tok, counts, Xp);
  // expert FFN: A = weights^T [M,K], Bt = activations [slots,K], C stored [slots,M]
  gemm_kernel<true><<<dim3(CAP / 128, DF / 128, NE), 256, 0, stream>>>(
      w1t, Xp, H, counts, DF, DM, (size_t)DM * DF, (size_t)CAP * DM, (size_t)CAP * DF);
  gemm_kernel<false><<<dim3(CAP / 128, DM / 128, NE), 256, 0, stream>>>(
      w2t, H, outp, counts, DM, DF, (size_t)DF * DM, (size_t)CAP * DF, (size_t)CAP * DM);
  // un-permute + weighted sum
  combine_kernel<<<T_TOK, 128, 0, stream>>>(outp, pos_slot, wts, out);
}